// Round 4
// baseline (323.518 us; speedup 1.0000x reference)
//
#include <hip/hip_runtime.h>

// VQ codebook argmin via bf16x3-split MFMA GEMM + quantized top-2 + fp32 rescore.
//   x_in: [B=16, EMB=64, CODES=16384] f32 ; E: [1024, 64] f32
//   out0: x_out [B,EMB,CODES] f32 = E[argmin] ; out1: indices as f32
// score = dot(x, E_k) - 0.5*||E_k||^2  (argmax == argmin of dist2)
// Scan computes 16384*(score+128) in the MFMA accumulator directly:
//   A = x * 2^14 (exact), C-init = wsh2[n] = 16384*(h[n]+128).
//
// R4 structure: 4-wave blocks, 32 queries/wave (128/block). B-fragment table
// staged chunk-wise (4 n-tiles = 16 KB) into double-buffered LDS shared by the
// 4 waves (exactly 32 KB => 5 blocks/CU; ~100 combined regs => 5 waves/SIMD).

#define BB 16
#define EMB 64
#define CODES 16384
#define NT 1024
#define NTILES 64
#define CHUNK 4          // n-tiles per LDS epoch
#define EPOCHS (NTILES / CHUNK)

typedef __attribute__((ext_vector_type(8))) short s16x8;   // 8 bf16 (4 VGPRs)
typedef __attribute__((ext_vector_type(4))) float f32x4;   // MFMA acc
typedef __attribute__((ext_vector_type(4))) int i32x4;
typedef unsigned int u32;

__device__ inline short bf16_hi(float f) { return (short)(__builtin_bit_cast(u32, f) >> 16); }
__device__ inline float hi_part(float f) { return __builtin_bit_cast(float, __builtin_bit_cast(u32, f) & 0xFFFF0000u); }
__device__ inline u32 umin_(u32 a, u32 b) { return a < b ? a : b; }
__device__ inline u32 umax_(u32 a, u32 b) { return a > b ? a : b; }

// ws layout:
//   [0, 256K)      : B-fragment table (64 n-tiles x 4096 B)
//   [266240, +4K)  : wsh  = -0.5*||E_n||^2            (epilogue rescore)
//   [270336, +4K)  : wsh2 = 16384*(wsh[n]+128)        (scan C-init)
#define WSE_OFF   0
#define WSH_OFF   266240
#define WSH2_OFF  270336

__global__ __launch_bounds__(256) void vq_prep(const float* __restrict__ E,
                                               char* __restrict__ wsE,
                                               float* __restrict__ wsh,
                                               float* __restrict__ wsh2) {
  const int bid = blockIdx.x, tid = threadIdx.x;
  if (bid < 32) {
    const int gid = bid * 256 + tid;              // 8192 tasks: nt(64) x ks(2) x lane(64)
    const int nt = gid >> 7, ks = (gid >> 6) & 1, lane = gid & 63;
    const int col = lane & 15, quad = lane >> 4;
    const int n = nt * 16 + col;
    const int k0 = ks * 32 + quad * 8;
    const float* ep = E + n * EMB + k0;
    s16x8 hv, lv;
    #pragma unroll
    for (int j = 0; j < 8; ++j) {
      float v = ep[j];
      float hf = hi_part(v);
      hv[j] = bf16_hi(v);
      lv[j] = bf16_hi(v - hf);   // v - hf exact in fp32
    }
    char* base = wsE + ((size_t)nt << 12) + ((size_t)ks << 10) + lane * 16;
    *(i32x4*)(base)        = __builtin_bit_cast(i32x4, hv);
    *(i32x4*)(base + 2048) = __builtin_bit_cast(i32x4, lv);
  } else {
    const int n = (bid - 32) * 256 + tid;
    if (n < NT) {
      const float4* ep = (const float4*)(E + n * EMB);
      float s = 0.f;
      #pragma unroll
      for (int g = 0; g < 16; ++g) { float4 v = ep[g]; s += v.x*v.x + v.y*v.y + v.z*v.z + v.w*v.w; }
      const float h = -0.5f * s;
      wsh[n] = h;
      wsh2[n] = 16384.f * (h + 128.f);
    }
  }
}

// Block = 256 threads (4 waves); wave handles 32 queries; block = 128 queries.
__global__ __launch_bounds__(256, 5) void vq_main(
    const float* __restrict__ x, const float* __restrict__ E,
    const char* __restrict__ wsE, const float* __restrict__ wsh,
    const float* __restrict__ wsh2,
    float* __restrict__ xout, float* __restrict__ iout) {
  __shared__ char smem[2 * CHUNK * 4096];   // exactly 32 KB; cand[] unioned in later
  const int tid = threadIdx.x;
  const int wave = tid >> 6, lane = tid & 63;
  const int col = lane & 15, quad = lane >> 4;
  const int b = blockIdx.y;
  const int c0 = blockIdx.x * 128;
  const int cw = c0 + wave * 32;

  // A fragments: lane holds A[m=col][k=quad*8+j] per (mt, ks); query scaled by 2^14.
  s16x8 ah[2][2], al[2][2];
  #pragma unroll
  for (int mt = 0; mt < 2; ++mt) {
    #pragma unroll
    for (int ks = 0; ks < 2; ++ks) {
      s16x8 hv, lv;
      #pragma unroll
      for (int j = 0; j < 8; ++j) {
        const int e = ks * 32 + quad * 8 + j;
        float v = x[((size_t)b * EMB + e) * CODES + (size_t)(cw + mt * 16 + col)] * 16384.f;
        float hf = hi_part(v);
        hv[j] = bf16_hi(v);
        lv[j] = bf16_hi(v - hf);
      }
      ah[mt][ks] = hv;
      al[mt][ks] = lv;
    }
  }

  // key = (u32)acc << 10 | (1023 - n); larger (1023-n) wins ties => earliest index.
  u32 k1[2][4], k2[2][4];
  #pragma unroll
  for (int mt = 0; mt < 2; ++mt)
    #pragma unroll
    for (int r = 0; r < 4; ++r) { k1[mt][r] = 0u; k2[mt][r] = 0u; }

  u32 inv = 1023u - (u32)col;
  const float* hp = wsh2 + col;

  // ---- LDS double-buffered B staging: wave w stages n-tile (c*4 + w) ----
  const char* gbase = wsE + wave * 4096 + lane * 16;
  i32x4 st0, st1, st2, st3;
  {
    const char* g = gbase;
    st0 = *(const i32x4*)(g);
    st1 = *(const i32x4*)(g + 1024);
    st2 = *(const i32x4*)(g + 2048);
    st3 = *(const i32x4*)(g + 3072);
    char* d = smem + wave * 4096 + lane * 16;
    *(i32x4*)(d)        = st0;
    *(i32x4*)(d + 1024) = st1;
    *(i32x4*)(d + 2048) = st2;
    *(i32x4*)(d + 3072) = st3;
  }
  __syncthreads();

  for (int c = 0; c < EPOCHS; ++c) {
    const char* rb = smem + (c & 1) * (CHUNK * 4096) + lane * 16;
    char* wb = smem + ((c + 1) & 1) * (CHUNK * 4096) + wave * 4096 + lane * 16;

    if (c < EPOCHS - 1) {                      // prefetch next chunk into regs
      const char* g = gbase + (size_t)(c + 1) * (CHUNK * 4096);
      st0 = *(const i32x4*)(g);
      st1 = *(const i32x4*)(g + 1024);
      st2 = *(const i32x4*)(g + 2048);
      st3 = *(const i32x4*)(g + 3072);
    }

    #pragma unroll
    for (int t = 0; t < CHUNK; ++t) {
      const char* p = rb + t * 4096;
      const s16x8 bh0 = __builtin_bit_cast(s16x8, *(const i32x4*)(p));
      const s16x8 bh1 = __builtin_bit_cast(s16x8, *(const i32x4*)(p + 1024));
      const s16x8 bl0 = __builtin_bit_cast(s16x8, *(const i32x4*)(p + 2048));
      const s16x8 bl1 = __builtin_bit_cast(s16x8, *(const i32x4*)(p + 3072));
      const float ch = hp[(c * CHUNK + t) * 16];

      f32x4 acc[2];
      #pragma unroll
      for (int mt = 0; mt < 2; ++mt) {
        acc[mt] = (f32x4){ch, ch, ch, ch};     // quantizer offset folded into C
        acc[mt] = __builtin_amdgcn_mfma_f32_16x16x32_bf16(ah[mt][0], bh0, acc[mt], 0, 0, 0);
        acc[mt] = __builtin_amdgcn_mfma_f32_16x16x32_bf16(ah[mt][1], bh1, acc[mt], 0, 0, 0);
        acc[mt] = __builtin_amdgcn_mfma_f32_16x16x32_bf16(al[mt][0], bh0, acc[mt], 0, 0, 0);
        acc[mt] = __builtin_amdgcn_mfma_f32_16x16x32_bf16(al[mt][1], bh1, acc[mt], 0, 0, 0);
        acc[mt] = __builtin_amdgcn_mfma_f32_16x16x32_bf16(ah[mt][0], bl0, acc[mt], 0, 0, 0);
        acc[mt] = __builtin_amdgcn_mfma_f32_16x16x32_bf16(ah[mt][1], bl1, acc[mt], 0, 0, 0);
      }

      #pragma unroll
      for (int mt = 0; mt < 2; ++mt) {
        #pragma unroll
        for (int r = 0; r < 4; ++r) {
          u32 q = (u32)acc[mt][r];             // v_cvt_u32_f32 (trunc), always >= 0
          u32 key = (q << 10) + inv;
          u32 tt = umin_(key, k1[mt][r]);
          k1[mt][r] = umax_(key, k1[mt][r]);
          k2[mt][r] = umax_(tt, k2[mt][r]);
        }
      }
      inv -= 16u;
    }

    if (c < EPOCHS - 1) {                      // commit prefetched chunk
      *(i32x4*)(wb)        = st0;
      *(i32x4*)(wb + 1024) = st1;
      *(i32x4*)(wb + 2048) = st2;
      *(i32x4*)(wb + 3072) = st3;
    }
    __syncthreads();
  }

  // Merge top-2 across the 16 col-lanes (xor 1,2,4,8 stays inside the quad group).
  uint2* cand = (uint2*)smem;                  // reuse staging LDS (all compute done)
  int* idxs = (int*)(smem + 1024);
  #pragma unroll
  for (int mt = 0; mt < 2; ++mt) {
    #pragma unroll
    for (int r = 0; r < 4; ++r) {
      u32 a1 = k1[mt][r], a2 = k2[mt][r];
      #pragma unroll
      for (int m = 1; m <= 8; m <<= 1) {
        u32 r1 = __shfl_xor(a1, m, 64);
        u32 r2 = __shfl_xor(a2, m, 64);
        u32 t = umin_(a1, r1);
        a1 = umax_(a1, r1);
        a2 = umax_(umax_(a2, r2), t);
      }
      // C/D layout: local query = wave*32 + mt*16 + quad*4 + r
      if (col == r) cand[wave * 32 + mt * 16 + quad * 4 + r] = make_uint2(a1, a2);
    }
  }
  __syncthreads();

  // Rescore (threads 0..127): exact fp32 on both candidates of query (c0+tid).
  if (tid < 128) {
    const u32 K1 = cand[tid].x, K2 = cand[tid].y;
    const int i1 = 1023 - (int)(K1 & 1023u);
    const int i2 = 1023 - (int)(K2 & 1023u);
    const float* xq = x + (size_t)b * EMB * CODES + (size_t)(c0 + tid);
    const float4* e1 = (const float4*)(E + i1 * EMB);
    const float4* e2 = (const float4*)(E + i2 * EMB);
    float d10 = 0, d11 = 0, d12 = 0, d13 = 0, d20 = 0, d21 = 0, d22 = 0, d23 = 0;
    #pragma unroll
    for (int g = 0; g < 16; ++g) {
      float4 a = e1[g], c4 = e2[g];
      float x0 = xq[(size_t)(4 * g + 0) * CODES];
      float x1 = xq[(size_t)(4 * g + 1) * CODES];
      float x2 = xq[(size_t)(4 * g + 2) * CODES];
      float x3 = xq[(size_t)(4 * g + 3) * CODES];
      d10 = fmaf(x0, a.x, d10);  d11 = fmaf(x1, a.y, d11);
      d12 = fmaf(x2, a.z, d12);  d13 = fmaf(x3, a.w, d13);
      d20 = fmaf(x0, c4.x, d20); d21 = fmaf(x1, c4.y, d21);
      d22 = fmaf(x2, c4.z, d22); d23 = fmaf(x3, c4.w, d23);
    }
    const float s1 = ((d10 + d11) + (d12 + d13)) + wsh[i1];
    const float s2 = ((d20 + d21) + (d22 + d23)) + wsh[i2];
    const bool take2 = (s2 > s1) || (s2 == s1 && i2 < i1);
    const int idx = take2 ? i2 : i1;
    idxs[tid] = idx;
    iout[(size_t)b * CODES + (size_t)(c0 + tid)] = (float)idx;
  }
  __syncthreads();

  // Output fan-out: all 256 threads; thread -> (query = tid&127, e-half = tid>>7).
  {
    const int q = tid & 127;
    const int eh = (tid >> 7) * 32;
    const int idx = idxs[q];
    const float* Er = E + idx * EMB + eh;
    float* xo = xout + ((size_t)b * EMB + eh) * CODES + (size_t)(c0 + q);
    #pragma unroll
    for (int e = 0; e < 32; ++e) xo[(size_t)e * CODES] = Er[e];
  }
}

extern "C" void kernel_launch(void* const* d_in, const int* in_sizes, int n_in,
                              void* d_out, int out_size, void* d_ws, size_t ws_size,
                              hipStream_t stream) {
  const float* x = (const float*)d_in[0];   // [16, 64, 16384]
  const float* E = (const float*)d_in[1];   // [1024, 64]
  float* xout = (float*)d_out;
  float* iout = (float*)d_out + (size_t)BB * EMB * CODES;

  char* wsE  = (char*)d_ws + WSE_OFF;
  float* wsh  = (float*)((char*)d_ws + WSH_OFF);
  float* wsh2 = (float*)((char*)d_ws + WSH2_OFF);

  vq_prep<<<36, 256, 0, stream>>>(E, wsE, wsh, wsh2);
  vq_main<<<dim3(CODES / 128, BB), 256, 0, stream>>>(x, E, wsE, wsh, wsh2, xout, iout);
}

// Round 5
// 203.067 us; speedup vs baseline: 1.5932x; 1.5932x over previous
//
#include <hip/hip_runtime.h>

// VQ codebook argmin via bf16x3-split MFMA GEMM + quantized top-2 + fp32 rescore.
//   x_in: [B=16, EMB=64, CODES=16384] f32 ; E: [1024, 64] f32
//   out0: x_out [B,EMB,CODES] f32 = E[argmin] ; out1: indices as f32
// score = dot(x, E_k) - 0.5*||E_k||^2  (argmax == argmin of dist2)
// Scan computes 16384*(score+128) in the MFMA accumulator directly:
//   A = x * 2^14 (exact), C-init = wsh2[n] = 16384*(h[n]+128).
//
// R5: 4-wave blocks, 64 queries/wave (256/block, 1024 blocks). B-fragment
// table staged per 4-tile epoch into double-buffered 32 KB LDS via
// global_load_lds (async, no staging VGPRs). launch_bounds(256,3) => 170-reg
// budget for a ~150-reg footprint (R4's (256,5)=102 caused the spill storm).

#define BB 16
#define EMB 64
#define CODES 16384
#define NT 1024
#define NTILES 64
#define CHUNK 4
#define EPOCHS (NTILES / CHUNK)

typedef __attribute__((ext_vector_type(8))) short s16x8;   // 8 bf16 (4 VGPRs)
typedef __attribute__((ext_vector_type(4))) float f32x4;   // MFMA acc
typedef __attribute__((ext_vector_type(4))) int i32x4;
typedef unsigned int u32;

__device__ inline short bf16_hi(float f) { return (short)(__builtin_bit_cast(u32, f) >> 16); }
__device__ inline float hi_part(float f) { return __builtin_bit_cast(float, __builtin_bit_cast(u32, f) & 0xFFFF0000u); }
__device__ inline u32 umin_(u32 a, u32 b) { return a < b ? a : b; }
__device__ inline u32 umax_(u32 a, u32 b) { return a > b ? a : b; }

// Async global->LDS, 16 B/lane. LDS dest is wave-uniform base + lane*16
// (m104/m108); pass the uniform base. LDS offset = low 32 bits of the generic
// address (CK-style int cast).
__device__ inline void async_copy16(const char* g, char* lds_base_uniform) {
  __builtin_amdgcn_global_load_lds(
      (const __attribute__((address_space(1))) unsigned int*)g,
      (__attribute__((address_space(3))) unsigned int*)(unsigned int)(unsigned long long)lds_base_uniform,
      16, 0, 0);
}

// ws layout:
//   [0, 256K)      : B-fragment table (64 n-tiles x 4096 B)
//   [266240, +4K)  : wsh  = -0.5*||E_n||^2            (epilogue rescore)
//   [270336, +4K)  : wsh2 = 16384*(wsh[n]+128)        (scan C-init)
#define WSE_OFF   0
#define WSH_OFF   266240
#define WSH2_OFF  270336

__global__ __launch_bounds__(256) void vq_prep(const float* __restrict__ E,
                                               char* __restrict__ wsE,
                                               float* __restrict__ wsh,
                                               float* __restrict__ wsh2) {
  const int bid = blockIdx.x, tid = threadIdx.x;
  if (bid < 32) {
    const int gid = bid * 256 + tid;              // 8192 tasks: nt(64) x ks(2) x lane(64)
    const int nt = gid >> 7, ks = (gid >> 6) & 1, lane = gid & 63;
    const int col = lane & 15, quad = lane >> 4;
    const int n = nt * 16 + col;
    const int k0 = ks * 32 + quad * 8;
    const float* ep = E + n * EMB + k0;
    s16x8 hv, lv;
    #pragma unroll
    for (int j = 0; j < 8; ++j) {
      float v = ep[j];
      float hf = hi_part(v);
      hv[j] = bf16_hi(v);
      lv[j] = bf16_hi(v - hf);   // v - hf exact in fp32
    }
    char* base = wsE + ((size_t)nt << 12) + ((size_t)ks << 10) + lane * 16;
    *(i32x4*)(base)        = __builtin_bit_cast(i32x4, hv);
    *(i32x4*)(base + 2048) = __builtin_bit_cast(i32x4, lv);
  } else {
    const int n = (bid - 32) * 256 + tid;
    if (n < NT) {
      const float4* ep = (const float4*)(E + n * EMB);
      float s = 0.f;
      #pragma unroll
      for (int g = 0; g < 16; ++g) { float4 v = ep[g]; s += v.x*v.x + v.y*v.y + v.z*v.z + v.w*v.w; }
      const float h = -0.5f * s;
      wsh[n] = h;
      wsh2[n] = 16384.f * (h + 128.f);
    }
  }
}

// Block = 256 threads (4 waves); wave scans 64 queries; block = 256 queries.
__global__ __launch_bounds__(256, 3) void vq_main(
    const float* __restrict__ x, const float* __restrict__ E,
    const char* __restrict__ wsE, const float* __restrict__ wsh,
    const float* __restrict__ wsh2,
    float* __restrict__ xout, float* __restrict__ iout) {
  __shared__ char smem[2 * CHUNK * 4096 + 4096];   // 32 KB B staging + 4 KB wsh2
  float* lh = (float*)(smem + 2 * CHUNK * 4096);
  const int tid = threadIdx.x;
  const int wave = tid >> 6, lane = tid & 63;
  const int col = lane & 15, quad = lane >> 4;
  const int b = blockIdx.y;
  const int c0 = blockIdx.x * 256;
  const int cw = c0 + wave * 64;

  // Stage wsh2 -> LDS (1024 floats) and kick off epoch-0 B staging.
  ((float4*)lh)[tid] = ((const float4*)wsh2)[tid];
  {
    const char* g = wsE + wave * 4096 + lane * 16;
    char* lb = smem + wave * 4096;                 // wave-uniform base
    async_copy16(g,        lb);
    async_copy16(g + 1024, lb + 1024);
    async_copy16(g + 2048, lb + 2048);
    async_copy16(g + 3072, lb + 3072);
  }

  // A fragments: lane holds A[m=col][k=quad*8+j] per (mt, ks); query scaled 2^14.
  s16x8 ah[4][2], al[4][2];
  #pragma unroll
  for (int mt = 0; mt < 4; ++mt) {
    #pragma unroll
    for (int ks = 0; ks < 2; ++ks) {
      s16x8 hv, lv;
      #pragma unroll
      for (int j = 0; j < 8; ++j) {
        const int e = ks * 32 + quad * 8 + j;
        float v = x[((size_t)b * EMB + e) * CODES + (size_t)(cw + mt * 16 + col)] * 16384.f;
        float hf = hi_part(v);
        hv[j] = bf16_hi(v);
        lv[j] = bf16_hi(v - hf);
      }
      ah[mt][ks] = hv;
      al[mt][ks] = lv;
    }
  }

  // key = (u32)acc << 10 | (1023 - n); larger (1023-n) wins ties => earliest idx.
  u32 k1[4][4], k2[4][4];
  #pragma unroll
  for (int mt = 0; mt < 4; ++mt)
    #pragma unroll
    for (int r = 0; r < 4; ++r) { k1[mt][r] = 0u; k2[mt][r] = 0u; }

  u32 inv = 1023u - (u32)col;

  __syncthreads();   // drains epoch-0 staging (vmcnt) + wsh2 LDS

  for (int c = 0; c < EPOCHS; ++c) {
    if (c < EPOCHS - 1) {                          // async-stage next epoch
      const char* g = wsE + (size_t)(c + 1) * (CHUNK * 4096) + wave * 4096 + lane * 16;
      char* lb = smem + ((c + 1) & 1) * (CHUNK * 4096) + wave * 4096;
      async_copy16(g,        lb);
      async_copy16(g + 1024, lb + 1024);
      async_copy16(g + 2048, lb + 2048);
      async_copy16(g + 3072, lb + 3072);
    }

    const char* rb = smem + (c & 1) * (CHUNK * 4096) + lane * 16;
    #pragma unroll
    for (int t = 0; t < CHUNK; ++t) {
      const char* p = rb + t * 4096;
      const s16x8 bh0 = __builtin_bit_cast(s16x8, *(const i32x4*)(p));
      const s16x8 bh1 = __builtin_bit_cast(s16x8, *(const i32x4*)(p + 1024));
      const s16x8 bl0 = __builtin_bit_cast(s16x8, *(const i32x4*)(p + 2048));
      const s16x8 bl1 = __builtin_bit_cast(s16x8, *(const i32x4*)(p + 3072));
      const float ch = lh[(c * CHUNK + t) * 16 + col];
      const f32x4 cq = (f32x4){ch, ch, ch, ch};    // C operand carries offset

      f32x4 acc[4];
      #pragma unroll
      for (int mt = 0; mt < 4; ++mt) {
        acc[mt] = __builtin_amdgcn_mfma_f32_16x16x32_bf16(ah[mt][0], bh0, cq, 0, 0, 0);
        acc[mt] = __builtin_amdgcn_mfma_f32_16x16x32_bf16(ah[mt][1], bh1, acc[mt], 0, 0, 0);
        acc[mt] = __builtin_amdgcn_mfma_f32_16x16x32_bf16(al[mt][0], bh0, acc[mt], 0, 0, 0);
        acc[mt] = __builtin_amdgcn_mfma_f32_16x16x32_bf16(al[mt][1], bh1, acc[mt], 0, 0, 0);
        acc[mt] = __builtin_amdgcn_mfma_f32_16x16x32_bf16(ah[mt][0], bl0, acc[mt], 0, 0, 0);
        acc[mt] = __builtin_amdgcn_mfma_f32_16x16x32_bf16(ah[mt][1], bl1, acc[mt], 0, 0, 0);
      }

      #pragma unroll
      for (int mt = 0; mt < 4; ++mt) {
        #pragma unroll
        for (int r = 0; r < 4; ++r) {
          u32 q = (u32)acc[mt][r];                 // v_cvt_u32_f32 (trunc), >= 0
          u32 key = (q << 10) + inv;
          u32 tt = umin_(key, k1[mt][r]);
          k1[mt][r] = umax_(key, k1[mt][r]);
          k2[mt][r] = umax_(tt, k2[mt][r]);
        }
      }
      inv -= 16u;
    }
    __syncthreads();   // drains next-epoch staging; protects buffer reuse
  }

  // Merge top-2 across the 16 col-lanes (xor 1,2,4,8 stays inside quad group).
  uint2* cand = (uint2*)smem;                      // staging LDS now free
  #pragma unroll
  for (int mt = 0; mt < 4; ++mt) {
    #pragma unroll
    for (int r = 0; r < 4; ++r) {
      u32 a1 = k1[mt][r], a2 = k2[mt][r];
      #pragma unroll
      for (int m = 1; m <= 8; m <<= 1) {
        u32 r1 = __shfl_xor(a1, m, 64);
        u32 r2 = __shfl_xor(a2, m, 64);
        u32 t = umin_(a1, r1);
        a1 = umax_(a1, r1);
        a2 = umax_(umax_(a2, r2), t);
      }
      // C/D layout: local query = wave*64 + mt*16 + quad*4 + r
      if (col == r) cand[wave * 64 + mt * 16 + quad * 4 + r] = make_uint2(a1, a2);
    }
  }
  __syncthreads();

  // Epilogue: thread tid owns query c0+tid. Exact fp32 rescore of the two
  // candidates, then gather winning E row and write outputs.
  const u32 K1 = cand[tid].x, K2 = cand[tid].y;
  const int i1 = 1023 - (int)(K1 & 1023u);
  const int i2 = 1023 - (int)(K2 & 1023u);
  const float* xq = x + (size_t)b * EMB * CODES + (size_t)(c0 + tid);
  const float4* e1 = (const float4*)(E + i1 * EMB);
  const float4* e2 = (const float4*)(E + i2 * EMB);
  float d10 = 0, d11 = 0, d12 = 0, d13 = 0, d20 = 0, d21 = 0, d22 = 0, d23 = 0;
  #pragma unroll
  for (int g = 0; g < 16; ++g) {
    float4 a = e1[g], c4 = e2[g];
    float x0 = xq[(size_t)(4 * g + 0) * CODES];
    float x1 = xq[(size_t)(4 * g + 1) * CODES];
    float x2 = xq[(size_t)(4 * g + 2) * CODES];
    float x3 = xq[(size_t)(4 * g + 3) * CODES];
    d10 = fmaf(x0, a.x, d10);  d11 = fmaf(x1, a.y, d11);
    d12 = fmaf(x2, a.z, d12);  d13 = fmaf(x3, a.w, d13);
    d20 = fmaf(x0, c4.x, d20); d21 = fmaf(x1, c4.y, d21);
    d22 = fmaf(x2, c4.z, d22); d23 = fmaf(x3, c4.w, d23);
  }
  const float s1 = ((d10 + d11) + (d12 + d13)) + wsh[i1];
  const float s2 = ((d20 + d21) + (d22 + d23)) + wsh[i2];
  const bool take2 = (s2 > s1) || (s2 == s1 && i2 < i1);
  const int idx = take2 ? i2 : i1;

  iout[(size_t)b * CODES + (size_t)(c0 + tid)] = (float)idx;
  const float* Er = E + idx * EMB;
  float* xo = xout + (size_t)b * EMB * CODES + (size_t)(c0 + tid);
  #pragma unroll
  for (int e = 0; e < EMB; ++e) xo[(size_t)e * CODES] = Er[e];
}

extern "C" void kernel_launch(void* const* d_in, const int* in_sizes, int n_in,
                              void* d_out, int out_size, void* d_ws, size_t ws_size,
                              hipStream_t stream) {
  const float* x = (const float*)d_in[0];   // [16, 64, 16384]
  const float* E = (const float*)d_in[1];   // [1024, 64]
  float* xout = (float*)d_out;
  float* iout = (float*)d_out + (size_t)BB * EMB * CODES;

  char* wsE  = (char*)d_ws + WSE_OFF;
  float* wsh  = (float*)((char*)d_ws + WSH_OFF);
  float* wsh2 = (float*)((char*)d_ws + WSH2_OFF);

  vq_prep<<<36, 256, 0, stream>>>(E, wsE, wsh, wsh2);
  vq_main<<<dim3(CODES / 256, BB), 256, 0, stream>>>(x, E, wsE, wsh, wsh2, xout, iout);
}

// Round 6
// 202.124 us; speedup vs baseline: 1.6006x; 1.0047x over previous
//
#include <hip/hip_runtime.h>

// VQ codebook argmin via bf16x3-split MFMA GEMM + quantized top-2 + fp32 rescore.
//   x_in: [B=16, EMB=64, CODES=16384] f32 ; E: [1024, 64] f32
//   out0: x_out [B,EMB,CODES] f32 = E[argmin] ; out1: indices as f32
// score = dot(x, E_k) - 0.5*||E_k||^2  (argmax == argmin of dist2)
// Scan computes 16384*(score+128) in the MFMA accumulator directly:
//   A = x * 2^14 (exact), C-init = wsh2[n] = 16384*(h[n]+128).
//
// R6: 32 queries/wave (2 m-tiles) to halve register footprint (~95 combined
// VGPR+AGPR) => 4 waves/SIMD at launch_bounds(256,4). 4-wave blocks (128 q),
// 2048 blocks. B staged per 4-tile epoch into double-buffered 32 KB LDS via
// async global_load_lds. (R5: Q=64 => ~180 regs => 2 waves/SIMD, 124 us.)

#define BB 16
#define EMB 64
#define CODES 16384
#define NT 1024
#define NTILES 64
#define CHUNK 4
#define EPOCHS (NTILES / CHUNK)
#define QPB 128          // queries per block

typedef __attribute__((ext_vector_type(8))) short s16x8;   // 8 bf16 (4 VGPRs)
typedef __attribute__((ext_vector_type(4))) float f32x4;   // MFMA acc
typedef __attribute__((ext_vector_type(4))) int i32x4;
typedef unsigned int u32;

__device__ inline short bf16_hi(float f) { return (short)(__builtin_bit_cast(u32, f) >> 16); }
__device__ inline float hi_part(float f) { return __builtin_bit_cast(float, __builtin_bit_cast(u32, f) & 0xFFFF0000u); }
__device__ inline u32 umin_(u32 a, u32 b) { return a < b ? a : b; }
__device__ inline u32 umax_(u32 a, u32 b) { return a > b ? a : b; }

// Async global->LDS, 16 B/lane; LDS dest = wave-uniform base + lane*16.
__device__ inline void async_copy16(const char* g, char* lds_base_uniform) {
  __builtin_amdgcn_global_load_lds(
      (const __attribute__((address_space(1))) unsigned int*)g,
      (__attribute__((address_space(3))) unsigned int*)(unsigned int)(unsigned long long)lds_base_uniform,
      16, 0, 0);
}

// ws layout:
//   [0, 256K)      : B-fragment table (64 n-tiles x 4096 B)
//   [266240, +4K)  : wsh  = -0.5*||E_n||^2            (epilogue rescore)
//   [270336, +4K)  : wsh2 = 16384*(wsh[n]+128)        (scan C-init)
#define WSE_OFF   0
#define WSH_OFF   266240
#define WSH2_OFF  270336

__global__ __launch_bounds__(256) void vq_prep(const float* __restrict__ E,
                                               char* __restrict__ wsE,
                                               float* __restrict__ wsh,
                                               float* __restrict__ wsh2) {
  const int bid = blockIdx.x, tid = threadIdx.x;
  if (bid < 32) {
    const int gid = bid * 256 + tid;              // 8192 tasks: nt(64) x ks(2) x lane(64)
    const int nt = gid >> 7, ks = (gid >> 6) & 1, lane = gid & 63;
    const int col = lane & 15, quad = lane >> 4;
    const int n = nt * 16 + col;
    const int k0 = ks * 32 + quad * 8;
    const float* ep = E + n * EMB + k0;
    s16x8 hv, lv;
    #pragma unroll
    for (int j = 0; j < 8; ++j) {
      float v = ep[j];
      float hf = hi_part(v);
      hv[j] = bf16_hi(v);
      lv[j] = bf16_hi(v - hf);   // v - hf exact in fp32
    }
    char* base = wsE + ((size_t)nt << 12) + ((size_t)ks << 10) + lane * 16;
    *(i32x4*)(base)        = __builtin_bit_cast(i32x4, hv);
    *(i32x4*)(base + 2048) = __builtin_bit_cast(i32x4, lv);
  } else {
    const int n = (bid - 32) * 256 + tid;
    if (n < NT) {
      const float4* ep = (const float4*)(E + n * EMB);
      float s = 0.f;
      #pragma unroll
      for (int g = 0; g < 16; ++g) { float4 v = ep[g]; s += v.x*v.x + v.y*v.y + v.z*v.z + v.w*v.w; }
      const float h = -0.5f * s;
      wsh[n] = h;
      wsh2[n] = 16384.f * (h + 128.f);
    }
  }
}

// Block = 256 threads (4 waves); wave scans 32 queries; block = 128 queries.
__global__ __launch_bounds__(256, 4) void vq_main(
    const float* __restrict__ x, const float* __restrict__ E,
    const char* __restrict__ wsE, const float* __restrict__ wsh,
    const float* __restrict__ wsh2,
    float* __restrict__ xout, float* __restrict__ iout) {
  __shared__ char smem[2 * CHUNK * 4096 + 4096];   // 32 KB B staging + 4 KB wsh2
  float* lh = (float*)(smem + 2 * CHUNK * 4096);
  const int tid = threadIdx.x;
  const int wave = tid >> 6, lane = tid & 63;
  const int col = lane & 15, quad = lane >> 4;
  const int b = blockIdx.y;
  const int c0 = blockIdx.x * QPB;
  const int cw = c0 + wave * 32;

  // Stage wsh2 -> LDS (1024 floats) and kick off epoch-0 B staging.
  ((float4*)lh)[tid] = ((const float4*)wsh2)[tid];
  {
    const char* g = wsE + wave * 4096 + lane * 16;
    char* lb = smem + wave * 4096;                 // wave-uniform base
    async_copy16(g,        lb);
    async_copy16(g + 1024, lb + 1024);
    async_copy16(g + 2048, lb + 2048);
    async_copy16(g + 3072, lb + 3072);
  }

  // A fragments: lane holds A[m=col][k=quad*8+j] per (mt, ks); query scaled 2^14.
  s16x8 ah[2][2], al[2][2];
  #pragma unroll
  for (int mt = 0; mt < 2; ++mt) {
    #pragma unroll
    for (int ks = 0; ks < 2; ++ks) {
      s16x8 hv, lv;
      #pragma unroll
      for (int j = 0; j < 8; ++j) {
        const int e = ks * 32 + quad * 8 + j;
        float v = x[((size_t)b * EMB + e) * CODES + (size_t)(cw + mt * 16 + col)] * 16384.f;
        float hf = hi_part(v);
        hv[j] = bf16_hi(v);
        lv[j] = bf16_hi(v - hf);
      }
      ah[mt][ks] = hv;
      al[mt][ks] = lv;
    }
  }

  // key = (u32)acc << 10 | (1023 - n); larger (1023-n) wins ties => earliest idx.
  u32 k1[2][4], k2[2][4];
  #pragma unroll
  for (int mt = 0; mt < 2; ++mt)
    #pragma unroll
    for (int r = 0; r < 4; ++r) { k1[mt][r] = 0u; k2[mt][r] = 0u; }

  u32 inv = 1023u - (u32)col;

  __syncthreads();   // drains epoch-0 staging (vmcnt) + wsh2 LDS

  for (int c = 0; c < EPOCHS; ++c) {
    if (c < EPOCHS - 1) {                          // async-stage next epoch
      const char* g = wsE + (size_t)(c + 1) * (CHUNK * 4096) + wave * 4096 + lane * 16;
      char* lb = smem + ((c + 1) & 1) * (CHUNK * 4096) + wave * 4096;
      async_copy16(g,        lb);
      async_copy16(g + 1024, lb + 1024);
      async_copy16(g + 2048, lb + 2048);
      async_copy16(g + 3072, lb + 3072);
    }

    const char* rb = smem + (c & 1) * (CHUNK * 4096) + lane * 16;
    #pragma unroll
    for (int t = 0; t < CHUNK; ++t) {
      const char* p = rb + t * 4096;
      const s16x8 bh0 = __builtin_bit_cast(s16x8, *(const i32x4*)(p));
      const s16x8 bh1 = __builtin_bit_cast(s16x8, *(const i32x4*)(p + 1024));
      const s16x8 bl0 = __builtin_bit_cast(s16x8, *(const i32x4*)(p + 2048));
      const s16x8 bl1 = __builtin_bit_cast(s16x8, *(const i32x4*)(p + 3072));
      const float ch = lh[(c * CHUNK + t) * 16 + col];
      const f32x4 cq = (f32x4){ch, ch, ch, ch};    // C operand carries offset

      f32x4 acc[2];
      #pragma unroll
      for (int mt = 0; mt < 2; ++mt) {
        acc[mt] = __builtin_amdgcn_mfma_f32_16x16x32_bf16(ah[mt][0], bh0, cq, 0, 0, 0);
        acc[mt] = __builtin_amdgcn_mfma_f32_16x16x32_bf16(ah[mt][1], bh1, acc[mt], 0, 0, 0);
        acc[mt] = __builtin_amdgcn_mfma_f32_16x16x32_bf16(al[mt][0], bh0, acc[mt], 0, 0, 0);
        acc[mt] = __builtin_amdgcn_mfma_f32_16x16x32_bf16(al[mt][1], bh1, acc[mt], 0, 0, 0);
        acc[mt] = __builtin_amdgcn_mfma_f32_16x16x32_bf16(ah[mt][0], bl0, acc[mt], 0, 0, 0);
        acc[mt] = __builtin_amdgcn_mfma_f32_16x16x32_bf16(ah[mt][1], bl1, acc[mt], 0, 0, 0);
      }

      #pragma unroll
      for (int mt = 0; mt < 2; ++mt) {
        #pragma unroll
        for (int r = 0; r < 4; ++r) {
          u32 q = (u32)acc[mt][r];                 // v_cvt_u32_f32 (trunc), >= 0
          u32 key = (q << 10) + inv;
          u32 tt = umin_(key, k1[mt][r]);
          k1[mt][r] = umax_(key, k1[mt][r]);
          k2[mt][r] = umax_(tt, k2[mt][r]);
        }
      }
      inv -= 16u;
    }
    __syncthreads();   // drains next-epoch staging; protects buffer reuse
  }

  // Merge top-2 across the 16 col-lanes (xor 1,2,4,8 stays inside quad group).
  uint2* cand = (uint2*)smem;                      // staging LDS now free
  int* idxs = (int*)(smem + 2048);
  #pragma unroll
  for (int mt = 0; mt < 2; ++mt) {
    #pragma unroll
    for (int r = 0; r < 4; ++r) {
      u32 a1 = k1[mt][r], a2 = k2[mt][r];
      #pragma unroll
      for (int m = 1; m <= 8; m <<= 1) {
        u32 r1 = __shfl_xor(a1, m, 64);
        u32 r2 = __shfl_xor(a2, m, 64);
        u32 t = umin_(a1, r1);
        a1 = umax_(a1, r1);
        a2 = umax_(umax_(a2, r2), t);
      }
      // C/D layout: local query = wave*32 + mt*16 + quad*4 + r
      if (col == r) cand[wave * 32 + mt * 16 + quad * 4 + r] = make_uint2(a1, a2);
    }
  }
  __syncthreads();

  // Rescore (threads 0..127): exact fp32 on both candidates of query (c0+tid).
  if (tid < QPB) {
    const u32 K1 = cand[tid].x, K2 = cand[tid].y;
    const int i1 = 1023 - (int)(K1 & 1023u);
    const int i2 = 1023 - (int)(K2 & 1023u);
    const float* xq = x + (size_t)b * EMB * CODES + (size_t)(c0 + tid);
    const float4* e1 = (const float4*)(E + i1 * EMB);
    const float4* e2 = (const float4*)(E + i2 * EMB);
    float d10 = 0, d11 = 0, d12 = 0, d13 = 0, d20 = 0, d21 = 0, d22 = 0, d23 = 0;
    #pragma unroll
    for (int g = 0; g < 16; ++g) {
      float4 a = e1[g], c4 = e2[g];
      float x0 = xq[(size_t)(4 * g + 0) * CODES];
      float x1 = xq[(size_t)(4 * g + 1) * CODES];
      float x2 = xq[(size_t)(4 * g + 2) * CODES];
      float x3 = xq[(size_t)(4 * g + 3) * CODES];
      d10 = fmaf(x0, a.x, d10);  d11 = fmaf(x1, a.y, d11);
      d12 = fmaf(x2, a.z, d12);  d13 = fmaf(x3, a.w, d13);
      d20 = fmaf(x0, c4.x, d20); d21 = fmaf(x1, c4.y, d21);
      d22 = fmaf(x2, c4.z, d22); d23 = fmaf(x3, c4.w, d23);
    }
    const float s1 = ((d10 + d11) + (d12 + d13)) + wsh[i1];
    const float s2 = ((d20 + d21) + (d22 + d23)) + wsh[i2];
    const bool take2 = (s2 > s1) || (s2 == s1 && i2 < i1);
    const int idx = take2 ? i2 : i1;
    idxs[tid] = idx;
    iout[(size_t)b * CODES + (size_t)(c0 + tid)] = (float)idx;
  }
  __syncthreads();

  // Output fan-out: all 256 threads; thread -> (query = tid&127, e-half = tid>>7).
  {
    const int q = tid & (QPB - 1);
    const int eh = (tid >> 7) * 32;
    const int idx = idxs[q];
    const float* Er = E + idx * EMB + eh;
    float* xo = xout + ((size_t)b * EMB + eh) * CODES + (size_t)(c0 + q);
    #pragma unroll
    for (int e = 0; e < 32; ++e) xo[(size_t)e * CODES] = Er[e];
  }
}

extern "C" void kernel_launch(void* const* d_in, const int* in_sizes, int n_in,
                              void* d_out, int out_size, void* d_ws, size_t ws_size,
                              hipStream_t stream) {
  const float* x = (const float*)d_in[0];   // [16, 64, 16384]
  const float* E = (const float*)d_in[1];   // [1024, 64]
  float* xout = (float*)d_out;
  float* iout = (float*)d_out + (size_t)BB * EMB * CODES;

  char* wsE  = (char*)d_ws + WSE_OFF;
  float* wsh  = (float*)((char*)d_ws + WSH_OFF);
  float* wsh2 = (float*)((char*)d_ws + WSH2_OFF);

  vq_prep<<<36, 256, 0, stream>>>(E, wsE, wsh, wsh2);
  vq_main<<<dim3(CODES / QPB, BB), 256, 0, stream>>>(x, E, wsE, wsh, wsh2, xout, iout);
}